// Round 6
// baseline (4081.394 us; speedup 1.0000x reference)
//
#include <hip/hip_runtime.h>
#include <math.h>

// FCLTCQNetwork: liquid-time-constant cell scan + MLP head.
// B=4096 T=128 D=64 U=64 A=8 QH=64 UNFOLDS=6.
// Round 5: DECISIVE EXPERIMENT — round-2's exact clean inner loop (per-sigmoid
// mix: readlane, fma, exp2, add, rcp, 2x fma; NO pairing, NO clamp) but with
// 8 waves/block x E=2 elements/wave (256 blocks, 2 waves/SIMD). Tests whether
// a second resident wave's VALU can issue under the other wave's 16-cy wave64
// transcendental occupancy. Win => trans unit is separate (continue stacking);
// flat => round-2 was the transcendental-issue roofline.
//   sigmoid(sigma*(x-mu)) = rcp(1 + exp2(k*x + c)), k=-log2e*sigma, c=log2e*sigma*mu
// Params packed float4 (k, c, w_signed, |w|) in LDS, one ds_read_b128/term.

namespace {

constexpr int kB = 4096, kT = 128, kD = 64, kU = 64, kA = 8, kQH = 64, kUnf = 6;
constexpr float kEps = 1e-8f;
constexpr float kLog2e = 1.4426950408889634f;
constexpr int kWaves = 8;             // waves per block (2 per SIMD)
constexpr int kEPW = 2;               // batch elements per wave
constexpr int kBlock = kWaves * 64;   // 512 threads
constexpr int kBPB = kWaves * kEPW;   // 16 batch elements per block

#if __has_builtin(__builtin_amdgcn_exp2f)
#define EXP2F(x) __builtin_amdgcn_exp2f(x)
#else
#define EXP2F(x) exp2f(x)
#endif

__device__ __forceinline__ float rcp_fast(float x) {
  return __builtin_amdgcn_rcpf(x);
}

__device__ __forceinline__ float bcast(float x, int l) {
  return __int_as_float(__builtin_amdgcn_readlane(__float_as_int(x), l));
}

__device__ __forceinline__ float softplus(float x) { return log1pf(expf(x)); }

__global__ __launch_bounds__(kBlock, 2)
void ltc_fused(const float* __restrict__ obs, const float* __restrict__ input_w,
               const float* __restrict__ input_b, const float* __restrict__ s_mu,
               const float* __restrict__ s_sigma, const float* __restrict__ s_w,
               const float* __restrict__ s_erev, const float* __restrict__ r_mu,
               const float* __restrict__ r_sigma, const float* __restrict__ r_w,
               const float* __restrict__ r_erev, const float* __restrict__ gleak,
               const float* __restrict__ vleak, const float* __restrict__ cm,
               const float* __restrict__ W1, const float* __restrict__ b1,
               const float* __restrict__ W2, const float* __restrict__ b2,
               float* __restrict__ q_out, float* __restrict__ h_out) {
  // Packed transformed params: (k, c, w_signed, |w|). 64KB + 64KB = 128KB.
  __shared__ float4 sp[kD * kU];  // sensory, layout [d][i]
  __shared__ float4 rp[kU * kU];  // recurrent, layout [j][i]

  const int tid = threadIdx.x;
  for (int idx = tid; idx < kD * kU; idx += kBlock) {
    const float sg = s_sigma[idx];
    const float swa = softplus(s_w[idx]);
    sp[idx] = make_float4(-kLog2e * sg, kLog2e * sg * s_mu[idx],
                          swa * s_erev[idx], swa);
    const float rg = r_sigma[idx];
    const float rwa = softplus(r_w[idx]);
    rp[idx] = make_float4(-kLog2e * rg, kLog2e * rg * r_mu[idx],
                          rwa * r_erev[idx], rwa);
  }
  __syncthreads();

  const int lane = tid & 63;
  const int wid = tid >> 6;
  const int b0 = (blockIdx.x * kWaves + wid) * kEPW;  // this wave's 2 elements

  // Per-neuron (lane = i) scalars.
  const float gl   = softplus(gleak[lane]);
  const float glvl = gl * vleak[lane];
  const float cmt  = softplus(cm[lane]) * (float)kUnf;
  const float iw   = input_w[lane];
  const float ib   = input_b[lane];

  const float* ob[kEPW];
#pragma unroll
  for (int e = 0; e < kEPW; ++e) ob[e] = obs + (size_t)(b0 + e) * kT * kD;

  float v[kEPW], o[kEPW];
#pragma unroll
  for (int e = 0; e < kEPW; ++e) {
    v[e] = 0.0f;
    o[e] = ob[e][lane];  // prefetch t=0
  }

#pragma unroll 1
  for (int t = 0; t < kT; ++t) {
    // prefetch next timestep's obs; latency hides behind this iteration
    const int tn = (t + 1 < kT) ? (t + 1) : t;
    float nx[kEPW];
#pragma unroll
    for (int e = 0; e < kEPW; ++e) nx[e] = ob[e][tn * kD + lane];

    float xi[kEPW];
#pragma unroll
    for (int e = 0; e < kEPW; ++e) xi[e] = fmaf(o[e], iw, ib);

    // Sensory synapse sums (depend only on x; once per timestep).
    float ns[kEPW], ds[kEPW];
#pragma unroll
    for (int e = 0; e < kEPW; ++e) { ns[e] = 0.0f; ds[e] = 0.0f; }
#pragma unroll 16
    for (int d = 0; d < kD; ++d) {
      const float4 p = sp[d * kU + lane];
#pragma unroll
      for (int e = 0; e < kEPW; ++e) {
        const float xd = bcast(xi[e], d);
        const float ex = EXP2F(fmaf(p.x, xd, p.y));
        const float g = rcp_fast(1.0f + ex);
        ns[e] = fmaf(g, p.z, ns[e]);
        ds[e] = fmaf(g, p.w, ds[e]);
      }
    }

    // ODE unfolds.
#pragma unroll 1
    for (int u = 0; u < kUnf; ++u) {
      float num[kEPW], den[kEPW];
#pragma unroll
      for (int e = 0; e < kEPW; ++e) { num[e] = 0.0f; den[e] = 0.0f; }
#pragma unroll 16
      for (int j = 0; j < kU; ++j) {
        const float4 p = rp[j * kU + lane];
#pragma unroll
        for (int e = 0; e < kEPW; ++e) {
          const float vj = bcast(v[e], j);
          const float ex = EXP2F(fmaf(p.x, vj, p.y));
          const float g = rcp_fast(1.0f + ex);
          num[e] = fmaf(g, p.z, num[e]);
          den[e] = fmaf(g, p.w, den[e]);
        }
      }
#pragma unroll
      for (int e = 0; e < kEPW; ++e) {
        const float nt = fmaf(cmt, v[e], glvl) + num[e] + ns[e];
        const float dt = cmt + gl + den[e] + ds[e] + kEps;
        v[e] = nt * rcp_fast(dt);
      }
    }

#pragma unroll
    for (int e = 0; e < kEPW; ++e) o[e] = nx[e];
  }

  // hidden output
#pragma unroll
  for (int e = 0; e < kEPW; ++e) h_out[(size_t)(b0 + e) * kU + lane] = v[e];

  // Head: h1 = relu(v @ W1 + b1); q = h1 @ W2 + b2. Once per batch, cheap.
  float h1[kEPW];
#pragma unroll
  for (int e = 0; e < kEPW; ++e) h1[e] = b1[lane];
#pragma unroll 16
  for (int j = 0; j < kU; ++j) {
    const float w1 = W1[j * kQH + lane];
#pragma unroll
    for (int e = 0; e < kEPW; ++e) h1[e] = fmaf(bcast(v[e], j), w1, h1[e]);
  }
#pragma unroll
  for (int e = 0; e < kEPW; ++e) h1[e] = fmaxf(h1[e], 0.0f);

  float qa[kEPW][kA];
#pragma unroll
  for (int a = 0; a < kA; ++a) {
    const float w2 = W2[lane * kA + a];
#pragma unroll
    for (int e = 0; e < kEPW; ++e) qa[e][a] = h1[e] * w2;
  }
#pragma unroll
  for (int s = 32; s > 0; s >>= 1) {
#pragma unroll
    for (int a = 0; a < kA; ++a) {
#pragma unroll
      for (int e = 0; e < kEPW; ++e) qa[e][a] += __shfl_xor(qa[e][a], s, 64);
    }
  }
  if (lane == 0) {
#pragma unroll
    for (int a = 0; a < kA; ++a) {
#pragma unroll
      for (int e = 0; e < kEPW; ++e) {
        q_out[(size_t)(b0 + e) * kA + a] = qa[e][a] + b2[a];
      }
    }
  }
}

}  // namespace

extern "C" void kernel_launch(void* const* d_in, const int* in_sizes, int n_in,
                              void* d_out, int out_size, void* d_ws, size_t ws_size,
                              hipStream_t stream) {
  const float* obs     = (const float*)d_in[0];
  const float* input_w = (const float*)d_in[1];
  const float* input_b = (const float*)d_in[2];
  const float* s_mu    = (const float*)d_in[3];
  const float* s_sigma = (const float*)d_in[4];
  const float* s_w     = (const float*)d_in[5];
  const float* s_erev  = (const float*)d_in[6];
  const float* r_mu    = (const float*)d_in[7];
  const float* r_sigma = (const float*)d_in[8];
  const float* r_w     = (const float*)d_in[9];
  const float* r_erev  = (const float*)d_in[10];
  const float* gleak   = (const float*)d_in[11];
  const float* vleak   = (const float*)d_in[12];
  const float* cm      = (const float*)d_in[13];
  const float* W1      = (const float*)d_in[14];
  const float* b1      = (const float*)d_in[15];
  const float* W2      = (const float*)d_in[16];
  const float* b2      = (const float*)d_in[17];

  float* q_out = (float*)d_out;
  float* h_out = q_out + (size_t)kB * kA;

  hipLaunchKernelGGL(ltc_fused, dim3(kB / kBPB), dim3(kBlock), 0, stream,
                     obs, input_w, input_b, s_mu, s_sigma, s_w, s_erev,
                     r_mu, r_sigma, r_w, r_erev, gleak, vleak, cm,
                     W1, b1, W2, b2, q_out, h_out);
}

// Round 7
// 3313.044 us; speedup vs baseline: 1.2319x; 1.2319x over previous
//
#include <hip/hip_runtime.h>
#include <math.h>

// FCLTCQNetwork: liquid-time-constant cell scan + MLP head.
// B=4096 T=128 D=64 U=64 A=8 QH=64 UNFOLDS=6.
// Round 6: machine model (R2/R3/R5) says time = sum of issue cycles
// (VALU 2cy, trans 16cy wave64; LDS issue free; extra waves don't help).
// Cut issue cycles per sigmoid from 42 -> ~35:
//  (a) rcp-pairing across ADJACENT j WITHIN an element (elements stay
//      independent -> 4 ILP chains, unlike R4's cross-element coupling):
//      R = rcp(dA*dB); gA = dB*R; gB = dA*R  (3 trans / 2 sigmoids)
//      recurrent needs no clamp: |v|<=1 inductively -> |z|<=21 -> dA*dB<=2^42.
//      sensory: one fmin(z,40) per sigmoid -> pair product <= 2^80, err 2^-40.
//  (b) broadcasts via per-wave LDS scratch + immediate-offset ds_read
//      (replaces v_readlane: moves 1 VALU op/sigmoid to the free LDS pipe).
//   sigmoid(sigma*(x-mu)) = rcp(1 + exp2(k*x + c)), k=-log2e*sigma, c=log2e*sigma*mu
// Params packed float4 (k, c, w_signed, |w|) in LDS, one ds_read_b128/term.

namespace {

constexpr int kB = 4096, kT = 128, kD = 64, kU = 64, kA = 8, kQH = 64, kUnf = 6;
constexpr float kEps = 1e-8f;
constexpr float kLog2e = 1.4426950408889634f;
constexpr float kSClamp = 40.0f;      // sensory z clamp (err 2^-40)
constexpr int kWaves = 4;             // waves per block (1 per SIMD)
constexpr int kEPW = 4;               // batch elements per wave
constexpr int kBlock = kWaves * 64;   // 256 threads
constexpr int kBPB = kWaves * kEPW;   // 16 batch elements per block

#if __has_builtin(__builtin_amdgcn_exp2f)
#define EXP2F(x) __builtin_amdgcn_exp2f(x)
#else
#define EXP2F(x) exp2f(x)
#endif

__device__ __forceinline__ float rcp_fast(float x) {
  return __builtin_amdgcn_rcpf(x);
}

__device__ __forceinline__ float bcast(float x, int l) {
  return __int_as_float(__builtin_amdgcn_readlane(__float_as_int(x), l));
}

__device__ __forceinline__ float softplus(float x) { return log1pf(expf(x)); }

__global__ __launch_bounds__(kBlock, 1)
void ltc_fused(const float* __restrict__ obs, const float* __restrict__ input_w,
               const float* __restrict__ input_b, const float* __restrict__ s_mu,
               const float* __restrict__ s_sigma, const float* __restrict__ s_w,
               const float* __restrict__ s_erev, const float* __restrict__ r_mu,
               const float* __restrict__ r_sigma, const float* __restrict__ r_w,
               const float* __restrict__ r_erev, const float* __restrict__ gleak,
               const float* __restrict__ vleak, const float* __restrict__ cm,
               const float* __restrict__ W1, const float* __restrict__ b1,
               const float* __restrict__ W2, const float* __restrict__ b2,
               float* __restrict__ q_out, float* __restrict__ h_out) {
  // Packed transformed params: (k, c, w_signed, |w|). 64KB + 64KB = 128KB.
  __shared__ float4 sp[kD * kU];  // sensory, layout [d][i]
  __shared__ float4 rp[kU * kU];  // recurrent, layout [j][i]
  // Per-wave broadcast scratch: xi (sensory phase) then v (each unfold).
  __shared__ float vbuf[kWaves][kEPW][kU];  // 4KB

  const int tid = threadIdx.x;
  for (int idx = tid; idx < kD * kU; idx += kBlock) {
    const float sg = s_sigma[idx];
    const float swa = softplus(s_w[idx]);
    sp[idx] = make_float4(-kLog2e * sg, kLog2e * sg * s_mu[idx],
                          swa * s_erev[idx], swa);
    const float rg = r_sigma[idx];
    const float rwa = softplus(r_w[idx]);
    rp[idx] = make_float4(-kLog2e * rg, kLog2e * rg * r_mu[idx],
                          rwa * r_erev[idx], rwa);
  }
  __syncthreads();

  const int lane = tid & 63;
  const int wid = tid >> 6;
  const int b0 = (blockIdx.x * kWaves + wid) * kEPW;  // this wave's 4 elements

  // Per-neuron (lane = i) scalars.
  const float gl   = softplus(gleak[lane]);
  const float glvl = gl * vleak[lane];
  const float cmt  = softplus(cm[lane]) * (float)kUnf;
  const float iw   = input_w[lane];
  const float ib   = input_b[lane];

  const float* ob[kEPW];
#pragma unroll
  for (int e = 0; e < kEPW; ++e) ob[e] = obs + (size_t)(b0 + e) * kT * kD;

  float v[kEPW], o[kEPW];
#pragma unroll
  for (int e = 0; e < kEPW; ++e) {
    v[e] = 0.0f;
    o[e] = ob[e][lane];  // prefetch t=0
  }

#pragma unroll 1
  for (int t = 0; t < kT; ++t) {
    // prefetch next timestep's obs; latency hides behind this iteration
    const int tn = (t + 1 < kT) ? (t + 1) : t;
    float nx[kEPW];
#pragma unroll
    for (int e = 0; e < kEPW; ++e) nx[e] = ob[e][tn * kD + lane];

    // Broadcast xi through per-wave LDS scratch (lane d reads vbuf[..][d]).
#pragma unroll
    for (int e = 0; e < kEPW; ++e) vbuf[wid][e][lane] = fmaf(o[e], iw, ib);

    // Sensory synapse sums: paired rcp across adjacent d, fmin clamp.
    float ns[kEPW], ds[kEPW];
#pragma unroll
    for (int e = 0; e < kEPW; ++e) { ns[e] = 0.0f; ds[e] = 0.0f; }
#pragma unroll 8
    for (int d = 0; d < kD; d += 2) {
      const float4 pA = sp[d * kU + lane];
      const float4 pB = sp[(d + 1) * kU + lane];
#pragma unroll
      for (int e = 0; e < kEPW; ++e) {
        const float xA = vbuf[wid][e][d];
        const float xB = vbuf[wid][e][d + 1];
        const float zA = fminf(fmaf(pA.x, xA, pA.y), kSClamp);
        const float zB = fminf(fmaf(pB.x, xB, pB.y), kSClamp);
        const float dA = 1.0f + EXP2F(zA);
        const float dB = 1.0f + EXP2F(zB);
        const float R = rcp_fast(dA * dB);
        const float gA = dB * R;
        const float gB = dA * R;
        ns[e] = fmaf(gA, pA.z, ns[e]);
        ds[e] = fmaf(gA, pA.w, ds[e]);
        ns[e] = fmaf(gB, pB.z, ns[e]);
        ds[e] = fmaf(gB, pB.w, ds[e]);
      }
    }

    // ODE unfolds. |v| <= 1 inductively -> |z| <= 21 -> no clamp needed.
#pragma unroll 1
    for (int u = 0; u < kUnf; ++u) {
      // broadcast v through LDS scratch
#pragma unroll
      for (int e = 0; e < kEPW; ++e) vbuf[wid][e][lane] = v[e];

      float num[kEPW], den[kEPW];
#pragma unroll
      for (int e = 0; e < kEPW; ++e) { num[e] = 0.0f; den[e] = 0.0f; }
#pragma unroll 8
      for (int j = 0; j < kU; j += 2) {
        const float4 pA = rp[j * kU + lane];
        const float4 pB = rp[(j + 1) * kU + lane];
#pragma unroll
        for (int e = 0; e < kEPW; ++e) {
          const float vA = vbuf[wid][e][j];
          const float vB = vbuf[wid][e][j + 1];
          const float zA = fmaf(pA.x, vA, pA.y);
          const float zB = fmaf(pB.x, vB, pB.y);
          const float dA = 1.0f + EXP2F(zA);
          const float dB = 1.0f + EXP2F(zB);
          const float R = rcp_fast(dA * dB);
          const float gA = dB * R;
          const float gB = dA * R;
          num[e] = fmaf(gA, pA.z, num[e]);
          den[e] = fmaf(gA, pA.w, den[e]);
          num[e] = fmaf(gB, pB.z, num[e]);
          den[e] = fmaf(gB, pB.w, den[e]);
        }
      }
#pragma unroll
      for (int e = 0; e < kEPW; ++e) {
        const float nt = fmaf(cmt, v[e], glvl) + num[e] + ns[e];
        const float dt = cmt + gl + den[e] + ds[e] + kEps;
        v[e] = nt * rcp_fast(dt);
      }
    }

#pragma unroll
    for (int e = 0; e < kEPW; ++e) o[e] = nx[e];
  }

  // hidden output
#pragma unroll
  for (int e = 0; e < kEPW; ++e) h_out[(size_t)(b0 + e) * kU + lane] = v[e];

  // Head: h1 = relu(v @ W1 + b1); q = h1 @ W2 + b2. Once per batch, cheap.
  float h1[kEPW];
#pragma unroll
  for (int e = 0; e < kEPW; ++e) h1[e] = b1[lane];
#pragma unroll 16
  for (int j = 0; j < kU; ++j) {
    const float w1 = W1[j * kQH + lane];
#pragma unroll
    for (int e = 0; e < kEPW; ++e) h1[e] = fmaf(bcast(v[e], j), w1, h1[e]);
  }
#pragma unroll
  for (int e = 0; e < kEPW; ++e) h1[e] = fmaxf(h1[e], 0.0f);

  float qa[kEPW][kA];
#pragma unroll
  for (int a = 0; a < kA; ++a) {
    const float w2 = W2[lane * kA + a];
#pragma unroll
    for (int e = 0; e < kEPW; ++e) qa[e][a] = h1[e] * w2;
  }
#pragma unroll
  for (int s = 32; s > 0; s >>= 1) {
#pragma unroll
    for (int a = 0; a < kA; ++a) {
#pragma unroll
      for (int e = 0; e < kEPW; ++e) qa[e][a] += __shfl_xor(qa[e][a], s, 64);
    }
  }
  if (lane == 0) {
#pragma unroll
    for (int a = 0; a < kA; ++a) {
#pragma unroll
      for (int e = 0; e < kEPW; ++e) {
        q_out[(size_t)(b0 + e) * kA + a] = qa[e][a] + b2[a];
      }
    }
  }
}

}  // namespace

extern "C" void kernel_launch(void* const* d_in, const int* in_sizes, int n_in,
                              void* d_out, int out_size, void* d_ws, size_t ws_size,
                              hipStream_t stream) {
  const float* obs     = (const float*)d_in[0];
  const float* input_w = (const float*)d_in[1];
  const float* input_b = (const float*)d_in[2];
  const float* s_mu    = (const float*)d_in[3];
  const float* s_sigma = (const float*)d_in[4];
  const float* s_w     = (const float*)d_in[5];
  const float* s_erev  = (const float*)d_in[6];
  const float* r_mu    = (const float*)d_in[7];
  const float* r_sigma = (const float*)d_in[8];
  const float* r_w     = (const float*)d_in[9];
  const float* r_erev  = (const float*)d_in[10];
  const float* gleak   = (const float*)d_in[11];
  const float* vleak   = (const float*)d_in[12];
  const float* cm      = (const float*)d_in[13];
  const float* W1      = (const float*)d_in[14];
  const float* b1      = (const float*)d_in[15];
  const float* W2      = (const float*)d_in[16];
  const float* b2      = (const float*)d_in[17];

  float* q_out = (float*)d_out;
  float* h_out = q_out + (size_t)kB * kA;

  hipLaunchKernelGGL(ltc_fused, dim3(kB / kBPB), dim3(kBlock), 0, stream,
                     obs, input_w, input_b, s_mu, s_sigma, s_w, s_erev,
                     r_mu, r_sigma, r_w, r_erev, gleak, vleak, cm,
                     W1, b1, W2, b2, q_out, h_out);
}

// Round 8
// 3281.905 us; speedup vs baseline: 1.2436x; 1.0095x over previous
//
#include <hip/hip_runtime.h>
#include <math.h>

// FCLTCQNetwork: liquid-time-constant cell scan + MLP head.
// B=4096 T=128 D=64 U=64 A=8 QH=64 UNFOLDS=6.
// Round 7: machine model = sum of issue cycles (VALU 2cy, trans 16cy wave64,
// shared issue port; LDS pipe must stay under compute). Changes vs R6:
//  (a) 4-way rcp sharing within an element (j-quad): 5 trans / 4 sigmoids.
//      R = rcp((dA*dB)*(dC*dD)); RAB = (dC*dD)*R; gA = dB*RAB; etc.
//      recurrent |z|<=21 -> product <= 2^84 (no clamp);
//      sensory clamp z<=30 -> product <= 2^120 (err 2^-30).
//  (b) vbuf broadcast reads as float4 (ds_read_b128, j..j+3 contiguous):
//      LDS/CU per quad-iter 384cy < 520cy compute -> LDS off critical path.
//  (c) 4-way rcp on the per-unfold final division (across elements).
//   sigmoid(sigma*(x-mu)) = rcp(1 + exp2(k*x + c)), k=-log2e*sigma, c=log2e*sigma*mu
// Params packed float4 (k, c, w_signed, |w|) in LDS, one ds_read_b128/term.

namespace {

constexpr int kB = 4096, kT = 128, kD = 64, kU = 64, kA = 8, kQH = 64, kUnf = 6;
constexpr float kEps = 1e-8f;
constexpr float kLog2e = 1.4426950408889634f;
constexpr float kSClamp = 30.0f;      // sensory z clamp (err 2^-30)
constexpr int kWaves = 4;             // waves per block (1 per SIMD)
constexpr int kEPW = 4;               // batch elements per wave
constexpr int kBlock = kWaves * 64;   // 256 threads
constexpr int kBPB = kWaves * kEPW;   // 16 batch elements per block

#if __has_builtin(__builtin_amdgcn_exp2f)
#define EXP2F(x) __builtin_amdgcn_exp2f(x)
#else
#define EXP2F(x) exp2f(x)
#endif

__device__ __forceinline__ float rcp_fast(float x) {
  return __builtin_amdgcn_rcpf(x);
}

__device__ __forceinline__ float bcast(float x, int l) {
  return __int_as_float(__builtin_amdgcn_readlane(__float_as_int(x), l));
}

__device__ __forceinline__ float softplus(float x) { return log1pf(expf(x)); }

__global__ __launch_bounds__(kBlock, 1)
void ltc_fused(const float* __restrict__ obs, const float* __restrict__ input_w,
               const float* __restrict__ input_b, const float* __restrict__ s_mu,
               const float* __restrict__ s_sigma, const float* __restrict__ s_w,
               const float* __restrict__ s_erev, const float* __restrict__ r_mu,
               const float* __restrict__ r_sigma, const float* __restrict__ r_w,
               const float* __restrict__ r_erev, const float* __restrict__ gleak,
               const float* __restrict__ vleak, const float* __restrict__ cm,
               const float* __restrict__ W1, const float* __restrict__ b1,
               const float* __restrict__ W2, const float* __restrict__ b2,
               float* __restrict__ q_out, float* __restrict__ h_out) {
  // Packed transformed params: (k, c, w_signed, |w|). 64KB + 64KB = 128KB.
  __shared__ float4 sp[kD * kU];  // sensory, layout [d][i]
  __shared__ float4 rp[kU * kU];  // recurrent, layout [j][i]
  // Per-wave broadcast scratch: xi (sensory phase) then v (each unfold).
  __shared__ __align__(16) float vbuf[kWaves][kEPW][kU];  // 4KB

  const int tid = threadIdx.x;
  for (int idx = tid; idx < kD * kU; idx += kBlock) {
    const float sg = s_sigma[idx];
    const float swa = softplus(s_w[idx]);
    sp[idx] = make_float4(-kLog2e * sg, kLog2e * sg * s_mu[idx],
                          swa * s_erev[idx], swa);
    const float rg = r_sigma[idx];
    const float rwa = softplus(r_w[idx]);
    rp[idx] = make_float4(-kLog2e * rg, kLog2e * rg * r_mu[idx],
                          rwa * r_erev[idx], rwa);
  }
  __syncthreads();

  const int lane = tid & 63;
  const int wid = tid >> 6;
  const int b0 = (blockIdx.x * kWaves + wid) * kEPW;  // this wave's 4 elements

  // Per-neuron (lane = i) scalars.
  const float gl   = softplus(gleak[lane]);
  const float glvl = gl * vleak[lane];
  const float cmt  = softplus(cm[lane]) * (float)kUnf;
  const float iw   = input_w[lane];
  const float ib   = input_b[lane];

  const float* ob[kEPW];
#pragma unroll
  for (int e = 0; e < kEPW; ++e) ob[e] = obs + (size_t)(b0 + e) * kT * kD;

  float v[kEPW], o[kEPW];
#pragma unroll
  for (int e = 0; e < kEPW; ++e) {
    v[e] = 0.0f;
    o[e] = ob[e][lane];  // prefetch t=0
  }

#pragma unroll 1
  for (int t = 0; t < kT; ++t) {
    // prefetch next timestep's obs; latency hides behind this iteration
    const int tn = (t + 1 < kT) ? (t + 1) : t;
    float nx[kEPW];
#pragma unroll
    for (int e = 0; e < kEPW; ++e) nx[e] = ob[e][tn * kD + lane];

    // Broadcast xi through per-wave LDS scratch (read back as float4).
#pragma unroll
    for (int e = 0; e < kEPW; ++e) vbuf[wid][e][lane] = fmaf(o[e], iw, ib);

    // Sensory synapse sums: 4-way shared rcp, clamped z.
    float ns[kEPW], ds[kEPW];
#pragma unroll
    for (int e = 0; e < kEPW; ++e) { ns[e] = 0.0f; ds[e] = 0.0f; }
#pragma unroll 4
    for (int d = 0; d < kD; d += 4) {
      const float4 pA = sp[(d + 0) * kU + lane];
      const float4 pB = sp[(d + 1) * kU + lane];
      const float4 pC = sp[(d + 2) * kU + lane];
      const float4 pD = sp[(d + 3) * kU + lane];
#pragma unroll
      for (int e = 0; e < kEPW; ++e) {
        const float4 x4 = *reinterpret_cast<const float4*>(&vbuf[wid][e][d]);
        const float zA = fminf(fmaf(pA.x, x4.x, pA.y), kSClamp);
        const float zB = fminf(fmaf(pB.x, x4.y, pB.y), kSClamp);
        const float zC = fminf(fmaf(pC.x, x4.z, pC.y), kSClamp);
        const float zD = fminf(fmaf(pD.x, x4.w, pD.y), kSClamp);
        const float dA = 1.0f + EXP2F(zA);
        const float dB = 1.0f + EXP2F(zB);
        const float dC = 1.0f + EXP2F(zC);
        const float dD = 1.0f + EXP2F(zD);
        const float pAB = dA * dB;
        const float pCD = dC * dD;
        const float R = rcp_fast(pAB * pCD);
        const float RAB = pCD * R;
        const float RCD = pAB * R;
        const float gA = dB * RAB;
        const float gB = dA * RAB;
        const float gC = dD * RCD;
        const float gD = dC * RCD;
        ns[e] = fmaf(gA, pA.z, ns[e]);
        ds[e] = fmaf(gA, pA.w, ds[e]);
        ns[e] = fmaf(gB, pB.z, ns[e]);
        ds[e] = fmaf(gB, pB.w, ds[e]);
        ns[e] = fmaf(gC, pC.z, ns[e]);
        ds[e] = fmaf(gC, pC.w, ds[e]);
        ns[e] = fmaf(gD, pD.z, ns[e]);
        ds[e] = fmaf(gD, pD.w, ds[e]);
      }
    }

    // ODE unfolds. |v| <= 1 inductively -> |z| <= 21 -> 4-product <= 2^84.
#pragma unroll 1
    for (int u = 0; u < kUnf; ++u) {
      // broadcast v through LDS scratch
#pragma unroll
      for (int e = 0; e < kEPW; ++e) vbuf[wid][e][lane] = v[e];

      float num[kEPW], den[kEPW];
#pragma unroll
      for (int e = 0; e < kEPW; ++e) { num[e] = 0.0f; den[e] = 0.0f; }
#pragma unroll 4
      for (int j = 0; j < kU; j += 4) {
        const float4 pA = rp[(j + 0) * kU + lane];
        const float4 pB = rp[(j + 1) * kU + lane];
        const float4 pC = rp[(j + 2) * kU + lane];
        const float4 pD = rp[(j + 3) * kU + lane];
#pragma unroll
        for (int e = 0; e < kEPW; ++e) {
          const float4 v4 = *reinterpret_cast<const float4*>(&vbuf[wid][e][j]);
          const float zA = fmaf(pA.x, v4.x, pA.y);
          const float zB = fmaf(pB.x, v4.y, pB.y);
          const float zC = fmaf(pC.x, v4.z, pC.y);
          const float zD = fmaf(pD.x, v4.w, pD.y);
          const float dA = 1.0f + EXP2F(zA);
          const float dB = 1.0f + EXP2F(zB);
          const float dC = 1.0f + EXP2F(zC);
          const float dD = 1.0f + EXP2F(zD);
          const float pAB = dA * dB;
          const float pCD = dC * dD;
          const float R = rcp_fast(pAB * pCD);
          const float RAB = pCD * R;
          const float RCD = pAB * R;
          const float gA = dB * RAB;
          const float gB = dA * RAB;
          const float gC = dD * RCD;
          const float gD = dC * RCD;
          num[e] = fmaf(gA, pA.z, num[e]);
          den[e] = fmaf(gA, pA.w, den[e]);
          num[e] = fmaf(gB, pB.z, num[e]);
          den[e] = fmaf(gB, pB.w, den[e]);
          num[e] = fmaf(gC, pC.z, num[e]);
          den[e] = fmaf(gC, pC.w, den[e]);
          num[e] = fmaf(gD, pD.z, num[e]);
          den[e] = fmaf(gD, pD.w, den[e]);
        }
      }
      // 4-way shared rcp for the final divisions (den ~ [1.5, ~90]).
      float nt[kEPW], dt[kEPW];
#pragma unroll
      for (int e = 0; e < kEPW; ++e) {
        nt[e] = fmaf(cmt, v[e], glvl) + num[e] + ns[e];
        dt[e] = cmt + gl + den[e] + ds[e] + kEps;
      }
      {
        const float p01 = dt[0] * dt[1];
        const float p23 = dt[2] * dt[3];
        const float R = rcp_fast(p01 * p23);
        const float R01 = p23 * R;
        const float R23 = p01 * R;
        v[0] = nt[0] * (dt[1] * R01);
        v[1] = nt[1] * (dt[0] * R01);
        v[2] = nt[2] * (dt[3] * R23);
        v[3] = nt[3] * (dt[2] * R23);
      }
    }

#pragma unroll
    for (int e = 0; e < kEPW; ++e) o[e] = nx[e];
  }

  // hidden output
#pragma unroll
  for (int e = 0; e < kEPW; ++e) h_out[(size_t)(b0 + e) * kU + lane] = v[e];

  // Head: h1 = relu(v @ W1 + b1); q = h1 @ W2 + b2. Once per batch, cheap.
  float h1[kEPW];
#pragma unroll
  for (int e = 0; e < kEPW; ++e) h1[e] = b1[lane];
#pragma unroll 16
  for (int j = 0; j < kU; ++j) {
    const float w1 = W1[j * kQH + lane];
#pragma unroll
    for (int e = 0; e < kEPW; ++e) h1[e] = fmaf(bcast(v[e], j), w1, h1[e]);
  }
#pragma unroll
  for (int e = 0; e < kEPW; ++e) h1[e] = fmaxf(h1[e], 0.0f);

  float qa[kEPW][kA];
#pragma unroll
  for (int a = 0; a < kA; ++a) {
    const float w2 = W2[lane * kA + a];
#pragma unroll
    for (int e = 0; e < kEPW; ++e) qa[e][a] = h1[e] * w2;
  }
#pragma unroll
  for (int s = 32; s > 0; s >>= 1) {
#pragma unroll
    for (int a = 0; a < kA; ++a) {
#pragma unroll
      for (int e = 0; e < kEPW; ++e) qa[e][a] += __shfl_xor(qa[e][a], s, 64);
    }
  }
  if (lane == 0) {
#pragma unroll
    for (int a = 0; a < kA; ++a) {
#pragma unroll
      for (int e = 0; e < kEPW; ++e) {
        q_out[(size_t)(b0 + e) * kA + a] = qa[e][a] + b2[a];
      }
    }
  }
}

}  // namespace

extern "C" void kernel_launch(void* const* d_in, const int* in_sizes, int n_in,
                              void* d_out, int out_size, void* d_ws, size_t ws_size,
                              hipStream_t stream) {
  const float* obs     = (const float*)d_in[0];
  const float* input_w = (const float*)d_in[1];
  const float* input_b = (const float*)d_in[2];
  const float* s_mu    = (const float*)d_in[3];
  const float* s_sigma = (const float*)d_in[4];
  const float* s_w     = (const float*)d_in[5];
  const float* s_erev  = (const float*)d_in[6];
  const float* r_mu    = (const float*)d_in[7];
  const float* r_sigma = (const float*)d_in[8];
  const float* r_w     = (const float*)d_in[9];
  const float* r_erev  = (const float*)d_in[10];
  const float* gleak   = (const float*)d_in[11];
  const float* vleak   = (const float*)d_in[12];
  const float* cm      = (const float*)d_in[13];
  const float* W1      = (const float*)d_in[14];
  const float* b1      = (const float*)d_in[15];
  const float* W2      = (const float*)d_in[16];
  const float* b2      = (const float*)d_in[17];

  float* q_out = (float*)d_out;
  float* h_out = q_out + (size_t)kB * kA;

  hipLaunchKernelGGL(ltc_fused, dim3(kB / kBPB), dim3(kBlock), 0, stream,
                     obs, input_w, input_b, s_mu, s_sigma, s_w, s_erev,
                     r_mu, r_sigma, r_w, r_erev, gleak, vleak, cm,
                     W1, b1, W2, b2, q_out, h_out);
}